// Round 13
// baseline (1030.904 us; speedup 1.0000x reference)
//
#include <hip/hip_runtime.h>
#include <stdint.h>

// CodebookWrapperLinear: out = x @ dequant(w)^T
//   x: (8192,4096) f32 ; codebook: (4,) f32 ; scale: (16384,128,1) f32 ;
//   indexes: (16384,128,32) i32 ; out: (8192,16384) f32
// R13: persistent blocks. grid=256 (1/CU); each block computes 8 tiles:
// n fixed = ((bid&1)*32 + bid>>3), m = ((bid&7)>>1)*8 + inner (grouped-m
// preserved: B panel reused by the block across all 8 m-tiles; per-XCD
// working set L3-resident). Interior K-schedule byte-identical to R12
// (verified: 60.3 MfmaUtil, 0 conflicts, 0 spill, FETCH 788MB).
// Inter-tile: epilogue stores -> next prologue stages -> VM6 (stores older,
// drain first; ledger semantics unchanged). Peel's last barrier certifies
// all ds_reads drained (final MFMAs register-only) -> stages WAR-safe.

typedef unsigned short u16;
typedef __attribute__((ext_vector_type(8))) __bf16 bf16x8;
typedef __attribute__((ext_vector_type(4))) float f32x4;

__device__ __forceinline__ uint32_t f2bf(float f) {
  uint32_t u = __builtin_bit_cast(uint32_t, f);
  return (u + 0x7FFFu + ((u >> 16) & 1u)) >> 16;  // RNE f32 -> bf16
}

__device__ __forceinline__ void gload16(const u16* g, u16* l) {
  __builtin_amdgcn_global_load_lds(
      (__attribute__((address_space(1))) void*)(g),
      (__attribute__((address_space(3))) void*)(l), 16, 0, 0);
}

__device__ __forceinline__ uint32_t sel4(uint32_t b0, uint32_t b1, uint32_t b2,
                                         uint32_t b3, int q) {
  uint32_t lo = (q & 1) ? b1 : b0;
  uint32_t hi = (q & 1) ? b3 : b2;
  return (q & 2) ? hi : lo;
}

// ---- x: f32 -> bf16, 8 elems/thread --------------------------------------
__global__ __launch_bounds__(256) void cvt_x(const float* __restrict__ x,
                                             u16* __restrict__ xb, int n8) {
  int t = blockIdx.x * 256 + threadIdx.x;
  if (t >= n8) return;
  const float4* xp = reinterpret_cast<const float4*>(x) + (size_t)t * 2;
  float4 v0 = xp[0], v1 = xp[1];
  uint4 o;
  o.x = f2bf(v0.x) | (f2bf(v0.y) << 16);
  o.y = f2bf(v0.z) | (f2bf(v0.w) << 16);
  o.z = f2bf(v1.x) | (f2bf(v1.y) << 16);
  o.w = f2bf(v1.z) | (f2bf(v1.w) << 16);
  reinterpret_cast<uint4*>(xb)[t] = o;
}

// ---- w dequant: one thread per 32-elem group -----------------------------
__global__ __launch_bounds__(256) void dequant_w(
    const float* __restrict__ cb, const float* __restrict__ scale,
    const int* __restrict__ idx, u16* __restrict__ w, int ngroups) {
  int t = blockIdx.x * 256 + threadIdx.x;
  if (t >= ngroups) return;
  float m = fmaxf(fmaxf(fabsf(cb[0]), fabsf(cb[1])),
                  fmaxf(fabsf(cb[2]), fabsf(cb[3])));
  m = fmaxf(m, 1e-8f);
  float s = expf(scale[t]) / m;
  uint32_t b0 = f2bf(cb[0] * s), b1 = f2bf(cb[1] * s);
  uint32_t b2 = f2bf(cb[2] * s), b3 = f2bf(cb[3] * s);
  const int4* ip = reinterpret_cast<const int4*>(idx) + (size_t)t * 8;
  uint4* op = reinterpret_cast<uint4*>(w) + (size_t)t * 4;
#pragma unroll
  for (int v = 0; v < 4; ++v) {
    int4 qa = ip[v * 2], qb = ip[v * 2 + 1];
    uint4 o;
    o.x = sel4(b0, b1, b2, b3, qa.x) | (sel4(b0, b1, b2, b3, qa.y) << 16);
    o.y = sel4(b0, b1, b2, b3, qa.z) | (sel4(b0, b1, b2, b3, qa.w) << 16);
    o.z = sel4(b0, b1, b2, b3, qb.x) | (sel4(b0, b1, b2, b3, qb.y) << 16);
    o.w = sel4(b0, b1, b2, b3, qb.z) | (sel4(b0, b1, b2, b3, qb.w) << 16);
    op[v] = o;
  }
}

// ---- 256x256 8-phase bf16 GEMM, persistent (8 tiles/block) ---------------
#define BM 256
#define BN 256
#define BK 64

__device__ __forceinline__ void memfence() { asm volatile("" ::: "memory"); }
__device__ __forceinline__ void BARx() {
  memfence();
  __builtin_amdgcn_s_barrier();
  memfence();
}

__global__ void __launch_bounds__(512, 2) gemm256(
    const u16* __restrict__ A, const u16* __restrict__ Bt,
    float* __restrict__ C, int M, int N, int K) {
  // [buf: even/odd K-tile][A|B][256 rows x 64 cols] bf16 = 128 KiB
  __shared__ u16 sm[2][2][BM * BK];

  const int bid = blockIdx.x;            // 256 blocks, 1/CU
  const int Gm = (bid & 7) >> 1;         // m-group 0..3 (per XCD-pair)
  const int nidx = ((bid & 1) << 5) | (bid >> 3);  // fixed n-tile 0..63
  const int n0 = nidx * BN;

  const int tid = threadIdx.x;
  const int lane = tid & 63;
  const int wid = tid >> 6;  // 8 waves: 2 (m: wr) x 4 (n: wc)
  const int wr = wid >> 2;
  const int wc = wid & 3;

  // staging: linear LDS dest (base + lane*16), pre-swizzled global source.
  // LDS (row R, slot p) holds global (row R, slot p ^ (R&7)); R&7=(lane>>3)&7.
  const int srow = wid * 8 + (lane >> 3);
  const int scol = (((lane & 7) ^ ((lane >> 3) & 7)) << 3);
  const u16* gB = Bt + (size_t)(n0 + srow) * K + scol;  // n fixed: hoisted

#define STAGE(b, op, h, gp, kc)                                   \
  {                                                               \
    u16* d = &sm[(b)][(op)][(h)*8192 + wid * 512];                \
    const u16* g = (gp) + (size_t)((h)*128) * K + (kc);           \
    gload16(g, d);                                                \
    gload16(g + (size_t)64 * K, d + 4096);                        \
  }

  // swizzled LDS fragment reads: row&7 == lane&7 for all fragment rows
  const int swzp0 = (((lane >> 4) ^ (lane & 7)) << 3);
  const int swzp1 = ((((lane >> 4) + 4) ^ (lane & 7)) << 3);
  const int lr = lane & 15;
  const int rAbase = (wr * 64 + lr) * BK;  // + q*8192 selects A half
  const int rBbase = (wc * 32 + lr) * BK;  // + pp*8192 selects B half

  bf16x8 af[4][2], bv0[2][2], bv1[2][2];

#define LOADA(b, q)                                               \
  {                                                               \
    const u16* p = &sm[(b)][0][rAbase + (q)*8192];                \
    af[0][0] = *(const bf16x8*)(p + swzp0);                       \
    af[0][1] = *(const bf16x8*)(p + swzp1);                       \
    af[1][0] = *(const bf16x8*)(p + 1024 + swzp0);                \
    af[1][1] = *(const bf16x8*)(p + 1024 + swzp1);                \
    af[2][0] = *(const bf16x8*)(p + 2048 + swzp0);                \
    af[2][1] = *(const bf16x8*)(p + 2048 + swzp1);                \
    af[3][0] = *(const bf16x8*)(p + 3072 + swzp0);                \
    af[3][1] = *(const bf16x8*)(p + 3072 + swzp1);                \
  }
#define LOADBX(BV, b, pp)                                         \
  {                                                               \
    const u16* p = &sm[(b)][1][rBbase + (pp)*8192];               \
    BV[0][0] = *(const bf16x8*)(p + swzp0);                       \
    BV[0][1] = *(const bf16x8*)(p + swzp1);                       \
    BV[1][0] = *(const bf16x8*)(p + 1024 + swzp0);                \
    BV[1][1] = *(const bf16x8*)(p + 1024 + swzp1);                \
  }
#define MFMAQ(q, pp, BV)                                                    \
  {                                                                         \
    __builtin_amdgcn_s_setprio(1);                                          \
    _Pragma("unroll") for (int i = 0; i < 4; ++i)                           \
        _Pragma("unroll") for (int j = 0; j < 2; ++j)                       \
            _Pragma("unroll") for (int ks = 0; ks < 2; ++ks)                \
                acc[(q)*4 + i][(pp)*2 + j] =                                \
        __builtin_amdgcn_mfma_f32_16x16x32_bf16(                            \
            af[i][ks], BV[j][ks], acc[(q)*4 + i][(pp)*2 + j], 0, 0, 0);     \
    __builtin_amdgcn_s_setprio(0);                                          \
  }
#define VM6 asm volatile("s_waitcnt vmcnt(6)" ::: "memory");
#define VM0 asm volatile("s_waitcnt vmcnt(0)" ::: "memory");

  f32x4 acc[8][4];

#pragma unroll 1
  for (int inner = 0; inner < 8; ++inner) {
    const int m0 = (Gm * 8 + inner) * BM;
    const u16* gA = A + (size_t)(m0 + srow) * K + scol;

#pragma unroll
    for (int i = 0; i < 8; ++i)
#pragma unroll
      for (int j = 0; j < 4; ++j) acc[i][j] = f32x4{0.f, 0.f, 0.f, 0.f};

    // prologue: tile0 all halves, then tile1 A0,B0,B1 (A1 at ph1).
    // For inner>0 the peel's last barrier certified all ds_reads drained,
    // and VM6 below drains the previous epilogue's (older) stores first.
    STAGE(0, 0, 0, gA, (size_t)0)
    STAGE(0, 1, 0, gB, (size_t)0)
    STAGE(0, 1, 1, gB, (size_t)0)
    STAGE(0, 0, 1, gA, (size_t)0)
    STAGE(1, 0, 0, gA, (size_t)64)
    STAGE(1, 1, 0, gB, (size_t)64)
    STAGE(1, 1, 1, gB, (size_t)64)
    VM6
    BARx();

#pragma unroll 1
    for (int i = 0; i < 31; ++i) {
      const size_t cT1 = (size_t)(2 * i + 1) * 64;
      const size_t cT2 = (size_t)(2 * i + 2) * 64;
      const size_t cT3 = (size_t)(2 * i + 3) * 64;
      // ph1: reads A0,B0(b0) then B1(b0) early; stage A1(b1) of t2i+1
      LOADA(0, 0) LOADBX(bv0, 0, 0) LOADBX(bv1, 0, 1)
      STAGE(1, 0, 1, gA, cT1)
      BARx(); MFMAQ(0, 0, bv0)
      // ph2: read-free
      BARx(); MFMAQ(0, 1, bv1)
      // ph3: reads A1(b0); stage A0+B0(b0) of t2i+2 (last read ph1)
      LOADA(0, 1)
      STAGE(0, 0, 0, gA, cT2) STAGE(0, 1, 0, gB, cT2)
      BARx(); MFMAQ(1, 1, bv1)
      // ph4: stage B1(b0) (last read ph1); W4 -> t2i+1 ready
      STAGE(0, 1, 1, gB, cT2)
      VM6
      BARx(); MFMAQ(1, 0, bv0)
      // ph5: reads A0,B0(b1) then B1(b1) early; stage A1(b0) (last read ph3)
      LOADA(1, 0) LOADBX(bv0, 1, 0) LOADBX(bv1, 1, 1)
      STAGE(0, 0, 1, gA, cT2)
      BARx(); MFMAQ(0, 0, bv0)
      // ph6: read-free
      BARx(); MFMAQ(0, 1, bv1)
      // ph7: reads A1(b1); stage A0+B0(b1) of t2i+3 (last read ph5)
      LOADA(1, 1)
      STAGE(1, 0, 0, gA, cT3) STAGE(1, 1, 0, gB, cT3)
      BARx(); MFMAQ(1, 1, bv1)
      // ph8: stage B1(b1) (last read ph5); W8 -> t2i+2 ready
      STAGE(1, 1, 1, gB, cT3)
      VM6
      BARx(); MFMAQ(1, 0, bv0)
    }

    // peeled final iter (tiles 62,63): only ph1 stage; VM0 at W4
    {
      const size_t cT1 = (size_t)63 * 64;
      LOADA(0, 0) LOADBX(bv0, 0, 0) LOADBX(bv1, 0, 1)
      STAGE(1, 0, 1, gA, cT1)
      BARx(); MFMAQ(0, 0, bv0)
      BARx(); MFMAQ(0, 1, bv1)
      LOADA(0, 1)
      BARx(); MFMAQ(1, 1, bv1)
      VM0
      BARx(); MFMAQ(1, 0, bv0)
      LOADA(1, 0) LOADBX(bv0, 1, 0) LOADBX(bv1, 1, 1)
      BARx(); MFMAQ(0, 0, bv0)
      BARx(); MFMAQ(0, 1, bv1)
      LOADA(1, 1)
      BARx(); MFMAQ(1, 1, bv1)
      BARx(); MFMAQ(1, 0, bv0)
      // last barrier above certifies all waves' ds_reads drained
      // (MFMAQ(1,0) is register-only) -> next inner's stages are WAR-safe.
    }

    // epilogue: C/D layout col=lane&15, row=(lane>>4)*4+reg
    const int crow0 = m0 + wr * 64 + ((lane >> 4) << 2);
    const int ccol0 = n0 + wc * 32 + (lane & 15);
#pragma unroll
    for (int q = 0; q < 2; ++q)
#pragma unroll
      for (int mi = 0; mi < 4; ++mi)
#pragma unroll
        for (int r = 0; r < 4; ++r) {
          float* cp = C + (size_t)(crow0 + q * 128 + mi * 16 + r) * N + ccol0;
#pragma unroll
          for (int pp = 0; pp < 2; ++pp)
#pragma unroll
            for (int j = 0; j < 2; ++j)
              cp[pp * 128 + j * 16] = acc[q * 4 + mi][pp * 2 + j][r];
        }
  }
}

extern "C" void kernel_launch(void* const* d_in, const int* in_sizes, int n_in,
                              void* d_out, int out_size, void* d_ws,
                              size_t ws_size, hipStream_t stream) {
  const float* x = (const float*)d_in[0];
  const float* cb = (const float*)d_in[1];
  const float* scale = (const float*)d_in[2];
  const int* idx = (const int*)d_in[3];
  float* out = (float*)d_out;

  constexpr int M = 4 * 2048;  // B*S
  constexpr int N = 16384;     // OUT
  constexpr int K = 4096;      // IN

  u16* xb = (u16*)d_ws;          // M*K bf16 = 64 MiB
  u16* wb = xb + (size_t)M * K;  // N*K bf16 = 128 MiB

  const int n8 = M * K / 8;
  cvt_x<<<dim3(n8 / 256), dim3(256), 0, stream>>>(x, xb, n8);
  const int ngroups = N * (K / 32);
  dequant_w<<<dim3(ngroups / 256), dim3(256), 0, stream>>>(cb, scale, idx, wb,
                                                           ngroups);
  gemm256<<<dim3(256), dim3(512), 0, stream>>>(xb, wb, out, M, N, K);
}

// Round 14
// 971.492 us; speedup vs baseline: 1.0612x; 1.0612x over previous
//
#include <hip/hip_runtime.h>
#include <stdint.h>

// CodebookWrapperLinear: out = x @ dequant(w)^T
//   x: (8192,4096) f32 ; codebook: (4,) f32 ; scale: (16384,128,1) f32 ;
//   indexes: (16384,128,32) i32 ; out: (8192,16384) f32
// R14 = R12 restored (best verified: total 972us, gemm ~880us, MfmaUtil
// 60.3, FETCH 788MB, zero spill/conflicts). R13's persistent blocks
// falsified (concurrent blocks spanned all n-panels -> FETCH 2.2GB, spill).
// Structure is at its documented plain-HIP ceiling (m201: 62.1% MfmaUtil):
// MFMA floor 4966cy/iter vs LDS-read floor 4608cy; register wall (256/wave)
// forbids deeper operand pipelining (R4/R6/R9 spills); barriers non-binding
// (R11); LLC effects non-binding (R10); low-precision closed (exp(scale)
// not e8m0-expressible; i8 rescale VALU > MFMA saving).

typedef unsigned short u16;
typedef __attribute__((ext_vector_type(8))) __bf16 bf16x8;
typedef __attribute__((ext_vector_type(4))) float f32x4;

__device__ __forceinline__ uint32_t f2bf(float f) {
  uint32_t u = __builtin_bit_cast(uint32_t, f);
  return (u + 0x7FFFu + ((u >> 16) & 1u)) >> 16;  // RNE f32 -> bf16
}

__device__ __forceinline__ void gload16(const u16* g, u16* l) {
  __builtin_amdgcn_global_load_lds(
      (__attribute__((address_space(1))) void*)(g),
      (__attribute__((address_space(3))) void*)(l), 16, 0, 0);
}

__device__ __forceinline__ uint32_t sel4(uint32_t b0, uint32_t b1, uint32_t b2,
                                         uint32_t b3, int q) {
  uint32_t lo = (q & 1) ? b1 : b0;
  uint32_t hi = (q & 1) ? b3 : b2;
  return (q & 2) ? hi : lo;
}

// ---- x: f32 -> bf16, 8 elems/thread --------------------------------------
__global__ __launch_bounds__(256) void cvt_x(const float* __restrict__ x,
                                             u16* __restrict__ xb, int n8) {
  int t = blockIdx.x * 256 + threadIdx.x;
  if (t >= n8) return;
  const float4* xp = reinterpret_cast<const float4*>(x) + (size_t)t * 2;
  float4 v0 = xp[0], v1 = xp[1];
  uint4 o;
  o.x = f2bf(v0.x) | (f2bf(v0.y) << 16);
  o.y = f2bf(v0.z) | (f2bf(v0.w) << 16);
  o.z = f2bf(v1.x) | (f2bf(v1.y) << 16);
  o.w = f2bf(v1.z) | (f2bf(v1.w) << 16);
  reinterpret_cast<uint4*>(xb)[t] = o;
}

// ---- w dequant: one thread per 32-elem group -----------------------------
__global__ __launch_bounds__(256) void dequant_w(
    const float* __restrict__ cb, const float* __restrict__ scale,
    const int* __restrict__ idx, u16* __restrict__ w, int ngroups) {
  int t = blockIdx.x * 256 + threadIdx.x;
  if (t >= ngroups) return;
  float m = fmaxf(fmaxf(fabsf(cb[0]), fabsf(cb[1])),
                  fmaxf(fabsf(cb[2]), fabsf(cb[3])));
  m = fmaxf(m, 1e-8f);
  float s = expf(scale[t]) / m;
  uint32_t b0 = f2bf(cb[0] * s), b1 = f2bf(cb[1] * s);
  uint32_t b2 = f2bf(cb[2] * s), b3 = f2bf(cb[3] * s);
  const int4* ip = reinterpret_cast<const int4*>(idx) + (size_t)t * 8;
  uint4* op = reinterpret_cast<uint4*>(w) + (size_t)t * 4;
#pragma unroll
  for (int v = 0; v < 4; ++v) {
    int4 qa = ip[v * 2], qb = ip[v * 2 + 1];
    uint4 o;
    o.x = sel4(b0, b1, b2, b3, qa.x) | (sel4(b0, b1, b2, b3, qa.y) << 16);
    o.y = sel4(b0, b1, b2, b3, qa.z) | (sel4(b0, b1, b2, b3, qa.w) << 16);
    o.z = sel4(b0, b1, b2, b3, qb.x) | (sel4(b0, b1, b2, b3, qb.y) << 16);
    o.w = sel4(b0, b1, b2, b3, qb.z) | (sel4(b0, b1, b2, b3, qb.w) << 16);
    op[v] = o;
  }
}

// ---- 256x256 8-phase bf16 GEMM: C[MxN] = A[MxK] * Bt[NxK]^T --------------
#define BM 256
#define BN 256
#define BK 64

__device__ __forceinline__ void memfence() { asm volatile("" ::: "memory"); }
__device__ __forceinline__ void BARx() {
  memfence();
  __builtin_amdgcn_s_barrier();
  memfence();
}

__global__ void __launch_bounds__(512, 2) gemm256(
    const u16* __restrict__ A, const u16* __restrict__ Bt,
    float* __restrict__ C, int M, int N, int K) {
  // [buf: even/odd K-tile][A|B][256 rows x 64 cols] bf16 = 128 KiB
  __shared__ u16 sm[2][2][BM * BK];

  // T1 XCD swizzle (2048 blocks, cpx=256/XCD) + grouped-m tile order:
  // 4 groups x (8 m-tiles x 64 n-tiles), m-fastest within a group.
  const int nwg = gridDim.x;
  const int cpx = nwg >> 3;
  const int bid = blockIdx.x;
  const int swz = (bid & 7) * cpx + (bid >> 3);
  const int G = swz >> 9;        // group of 512 blocks = 8 m-rows
  const int r = swz & 511;
  const int m0 = (G * 8 + (r & 7)) * BM;
  const int n0 = (r >> 3) * BN;

  const int tid = threadIdx.x;
  const int lane = tid & 63;
  const int wid = tid >> 6;  // 8 waves: 2 (m: wr) x 4 (n: wc)
  const int wr = wid >> 2;
  const int wc = wid & 3;

  // staging: linear LDS dest (base + lane*16), pre-swizzled global source.
  // LDS (row R, slot p) holds global (row R, slot p ^ (R&7)); R&7=(lane>>3)&7.
  const int srow = wid * 8 + (lane >> 3);
  const int scol = (((lane & 7) ^ ((lane >> 3) & 7)) << 3);
  const u16* gA = A + (size_t)(m0 + srow) * K + scol;
  const u16* gB = Bt + (size_t)(n0 + srow) * K + scol;

  // STAGE one contiguous 128-row half: op 0=A 1=B, h = half, kc = K-col off
#define STAGE(b, op, h, gp, kc)                                   \
  {                                                               \
    u16* d = &sm[(b)][(op)][(h)*8192 + wid * 512];                \
    const u16* g = (gp) + (size_t)((h)*128) * K + (kc);           \
    gload16(g, d);                                                \
    gload16(g + (size_t)64 * K, d + 4096);                        \
  }

  // swizzled LDS fragment reads: row&7 == lane&7 for all fragment rows
  const int swzp0 = (((lane >> 4) ^ (lane & 7)) << 3);
  const int swzp1 = ((((lane >> 4) + 4) ^ (lane & 7)) << 3);
  const int lr = lane & 15;
  const int rAbase = (wr * 64 + lr) * BK;  // + q*8192 selects A half
  const int rBbase = (wc * 32 + lr) * BK;  // + pp*8192 selects B half

  bf16x8 af[4][2], bv0[2][2], bv1[2][2];

#define LOADA(b, q)                                               \
  {                                                               \
    const u16* p = &sm[(b)][0][rAbase + (q)*8192];                \
    af[0][0] = *(const bf16x8*)(p + swzp0);                       \
    af[0][1] = *(const bf16x8*)(p + swzp1);                       \
    af[1][0] = *(const bf16x8*)(p + 1024 + swzp0);                \
    af[1][1] = *(const bf16x8*)(p + 1024 + swzp1);                \
    af[2][0] = *(const bf16x8*)(p + 2048 + swzp0);                \
    af[2][1] = *(const bf16x8*)(p + 2048 + swzp1);                \
    af[3][0] = *(const bf16x8*)(p + 3072 + swzp0);                \
    af[3][1] = *(const bf16x8*)(p + 3072 + swzp1);                \
  }
#define LOADBX(BV, b, pp)                                         \
  {                                                               \
    const u16* p = &sm[(b)][1][rBbase + (pp)*8192];               \
    BV[0][0] = *(const bf16x8*)(p + swzp0);                       \
    BV[0][1] = *(const bf16x8*)(p + swzp1);                       \
    BV[1][0] = *(const bf16x8*)(p + 1024 + swzp0);                \
    BV[1][1] = *(const bf16x8*)(p + 1024 + swzp1);                \
  }
#define MFMAQ(q, pp, BV)                                                    \
  {                                                                         \
    __builtin_amdgcn_s_setprio(1);                                          \
    _Pragma("unroll") for (int i = 0; i < 4; ++i)                           \
        _Pragma("unroll") for (int j = 0; j < 2; ++j)                       \
            _Pragma("unroll") for (int ks = 0; ks < 2; ++ks)                \
                acc[(q)*4 + i][(pp)*2 + j] =                                \
        __builtin_amdgcn_mfma_f32_16x16x32_bf16(                            \
            af[i][ks], BV[j][ks], acc[(q)*4 + i][(pp)*2 + j], 0, 0, 0);     \
    __builtin_amdgcn_s_setprio(0);                                          \
  }
#define VM6 asm volatile("s_waitcnt vmcnt(6)" ::: "memory");
#define VM0 asm volatile("s_waitcnt vmcnt(0)" ::: "memory");

  f32x4 acc[8][4];
#pragma unroll
  for (int i = 0; i < 8; ++i)
#pragma unroll
    for (int j = 0; j < 4; ++j) acc[i][j] = f32x4{0.f, 0.f, 0.f, 0.f};

  // ---- prologue: tile0 all halves, then tile1 A0,B0,B1 (A1 at ph1) ------
  STAGE(0, 0, 0, gA, (size_t)0)    // t0 A0(b0)
  STAGE(0, 1, 0, gB, (size_t)0)    // t0 B0(b0)
  STAGE(0, 1, 1, gB, (size_t)0)    // t0 B1(b0)
  STAGE(0, 0, 1, gA, (size_t)0)    // t0 A1(b0)
  STAGE(1, 0, 0, gA, (size_t)64)   // t1 A0(b1)
  STAGE(1, 1, 0, gB, (size_t)64)   // t1 B0(b1)
  STAGE(1, 1, 1, gB, (size_t)64)   // t1 B1(b1)
  VM6  // 8 oldest of 14 = tile0 fully landed
  BARx();

  // ---- main loop: iter i computes tiles 2i (b0), 2i+1 (b1) --------------
  // Phase p = [reads_p | stages_p | (VM) | BAR | MFMA_p]; one barrier/phase.
  // bv1 read one phase early (last in issue order): its drain hides under
  // the current phase's MFMA; ph2/ph6 are read-free.
#pragma unroll 1
  for (int i = 0; i < 31; ++i) {
    const size_t cT1 = (size_t)(2 * i + 1) * 64;  // tile 2i+1 final half
    const size_t cT2 = (size_t)(2 * i + 2) * 64;  // -> b0
    const size_t cT3 = (size_t)(2 * i + 3) * 64;  // -> b1
    // ph1: reads A0,B0(b0) then B1(b0) early; stage A1(b1) of t2i+1
    LOADA(0, 0) LOADBX(bv0, 0, 0) LOADBX(bv1, 0, 1)
    STAGE(1, 0, 1, gA, cT1)
    BARx(); MFMAQ(0, 0, bv0)
    // ph2: read-free (bv1 prefetched in ph1)
    BARx(); MFMAQ(0, 1, bv1)
    // ph3: reads A1(b0); stage A0(b0)+B0(b0) of t2i+2 (last read ph1)
    LOADA(0, 1)
    STAGE(0, 0, 0, gA, cT2) STAGE(0, 1, 0, gB, cT2)
    BARx(); MFMAQ(1, 1, bv1)
    // ph4: no reads; stage B1(b0) (last read ph1, +3); W4 -> t2i+1 ready
    STAGE(0, 1, 1, gB, cT2)
    VM6
    BARx(); MFMAQ(1, 0, bv0)
    // ph5: reads A0,B0(b1) then B1(b1) early; stage A1(b0) (last read ph3)
    LOADA(1, 0) LOADBX(bv0, 1, 0) LOADBX(bv1, 1, 1)
    STAGE(0, 0, 1, gA, cT2)
    BARx(); MFMAQ(0, 0, bv0)
    // ph6: read-free
    BARx(); MFMAQ(0, 1, bv1)
    // ph7: reads A1(b1); stage A0(b1)+B0(b1) of t2i+3 (last read ph5)
    LOADA(1, 1)
    STAGE(1, 0, 0, gA, cT3) STAGE(1, 1, 0, gB, cT3)
    BARx(); MFMAQ(1, 1, bv1)
    // ph8: no reads; stage B1(b1) (last read ph5, +3); W8 -> t2i+2 ready
    STAGE(1, 1, 1, gB, cT3)
    VM6
    BARx(); MFMAQ(1, 0, bv0)
  }

  // ---- peeled final iter (tiles 62,63): only ph1 stage; VM0 at W4 -------
  {
    const size_t cT1 = (size_t)63 * 64;
    LOADA(0, 0) LOADBX(bv0, 0, 0) LOADBX(bv1, 0, 1)
    STAGE(1, 0, 1, gA, cT1)
    BARx(); MFMAQ(0, 0, bv0)
    BARx(); MFMAQ(0, 1, bv1)
    LOADA(0, 1)
    BARx(); MFMAQ(1, 1, bv1)
    VM0
    BARx(); MFMAQ(1, 0, bv0)
    LOADA(1, 0) LOADBX(bv0, 1, 0) LOADBX(bv1, 1, 1)
    BARx(); MFMAQ(0, 0, bv0)
    BARx(); MFMAQ(0, 1, bv1)
    LOADA(1, 1)
    BARx(); MFMAQ(1, 1, bv1)
    BARx(); MFMAQ(1, 0, bv0)
  }

  // ---- epilogue: C/D layout col=lane&15, row=(lane>>4)*4+reg ------------
  const int crow0 = m0 + wr * 64 + ((lane >> 4) << 2);
  const int ccol0 = n0 + wc * 32 + (lane & 15);
#pragma unroll
  for (int q = 0; q < 2; ++q)
#pragma unroll
    for (int mi = 0; mi < 4; ++mi)
#pragma unroll
      for (int r = 0; r < 4; ++r) {
        float* cp = C + (size_t)(crow0 + q * 128 + mi * 16 + r) * N + ccol0;
#pragma unroll
        for (int pp = 0; pp < 2; ++pp)
#pragma unroll
          for (int j = 0; j < 2; ++j)
            cp[pp * 128 + j * 16] = acc[q * 4 + mi][pp * 2 + j][r];
      }
}

extern "C" void kernel_launch(void* const* d_in, const int* in_sizes, int n_in,
                              void* d_out, int out_size, void* d_ws,
                              size_t ws_size, hipStream_t stream) {
  const float* x = (const float*)d_in[0];
  const float* cb = (const float*)d_in[1];
  const float* scale = (const float*)d_in[2];
  const int* idx = (const int*)d_in[3];
  float* out = (float*)d_out;

  constexpr int M = 4 * 2048;  // B*S
  constexpr int N = 16384;     // OUT
  constexpr int K = 4096;      // IN

  u16* xb = (u16*)d_ws;          // M*K bf16 = 64 MiB
  u16* wb = xb + (size_t)M * K;  // N*K bf16 = 128 MiB

  const int n8 = M * K / 8;
  cvt_x<<<dim3(n8 / 256), dim3(256), 0, stream>>>(x, xb, n8);
  const int ngroups = N * (K / 32);
  dequant_w<<<dim3(ngroups / 256), dim3(256), 0, stream>>>(cb, scale, idx, wb,
                                                           ngroups);
  gemm256<<<dim3((M / BM) * (N / BN)), dim3(512), 0, stream>>>(xb, wb, out, M,
                                                               N, K);
}